// Round 1
// baseline (5797.047 us; speedup 1.0000x reference)
//
#include <hip/hip_runtime.h>

#define TPB 256

__device__ __forceinline__ void gatomic_add(float* p, float v) {
  unsafeAtomicAdd(p, v);  // hardware global_atomic_add_f32 on gfx90a+
}

__global__ __launch_bounds__(TPB) void k_init_deg(float* __restrict__ deg, int n) {
  int i = blockIdx.x * TPB + threadIdx.x;
  if (i < n) deg[i] = 1.0f;  // self-loop
}

__global__ __launch_bounds__(TPB) void k_count_deg(float* __restrict__ deg,
                                                   const int* __restrict__ ei,
                                                   long long E) {
  long long e = (long long)blockIdx.x * TPB + threadIdx.x;
  if (e < E) gatomic_add(&deg[ei[E + e]], 1.0f);
}

__global__ __launch_bounds__(TPB) void k_dinv(float* __restrict__ d, int n) {
  int i = blockIdx.x * TPB + threadIdx.x;
  if (i < n) d[i] = rsqrtf(d[i]);
}

__global__ __launch_bounds__(TPB) void k_edge_norm(float* __restrict__ norm,
                                                   const float* __restrict__ dinv,
                                                   const int* __restrict__ ei,
                                                   long long E) {
  long long e = (long long)blockIdx.x * TPB + threadIdx.x;
  if (e < E) norm[e] = dinv[ei[e]] * dinv[ei[E + e]];
}

// C[N,128] = (RELU? relu(A) : A)[N,128] @ W[128,128], f32 vector FMA.
// W staged in LDS (64KB). Block = 256 threads = 8 row-groups x 32 col-groups.
// Each thread: 8 rows x 4 cols (float4 accumulators).
template <int RELU>
__global__ __launch_bounds__(TPB) void k_gemm128(const float* __restrict__ A,
                                                 const float* __restrict__ W,
                                                 float* __restrict__ C, int N) {
  __shared__ float Wlds[128 * 128];
  {
    const float4* W4 = (const float4*)W;
    float4* Wl4w = (float4*)Wlds;
    for (int i = threadIdx.x; i < 128 * 32; i += TPB) Wl4w[i] = W4[i];
  }
  __syncthreads();
  const float4* Wl4 = (const float4*)Wlds;
  const int rt = threadIdx.x >> 5;   // 0..7
  const int cg = threadIdx.x & 31;   // 0..31
  const float4* A4 = (const float4*)A;
  float4* C4 = (float4*)C;

  for (long long row0 = (long long)blockIdx.x * 64; row0 < N;
       row0 += (long long)gridDim.x * 64) {
    const long long rbase = row0 + (long long)rt * 8;
    float4 acc[8];
#pragma unroll
    for (int i = 0; i < 8; ++i) acc[i] = make_float4(0.f, 0.f, 0.f, 0.f);

    for (int kk = 0; kk < 32; ++kk) {   // k in chunks of 4
      float4 av[8];
#pragma unroll
      for (int i = 0; i < 8; ++i) {
        long long r = rbase + i;
        av[i] = (r < N) ? A4[r * 32 + kk] : make_float4(0.f, 0.f, 0.f, 0.f);
        if (RELU) {
          av[i].x = fmaxf(av[i].x, 0.f);
          av[i].y = fmaxf(av[i].y, 0.f);
          av[i].z = fmaxf(av[i].z, 0.f);
          av[i].w = fmaxf(av[i].w, 0.f);
        }
      }
#pragma unroll
      for (int j = 0; j < 4; ++j) {
        float4 w = Wl4[(kk * 4 + j) * 32 + cg];
#pragma unroll
        for (int i = 0; i < 8; ++i) {
          float aij = ((const float*)&av[i])[j];
          acc[i].x = fmaf(aij, w.x, acc[i].x);
          acc[i].y = fmaf(aij, w.y, acc[i].y);
          acc[i].z = fmaf(aij, w.z, acc[i].z);
          acc[i].w = fmaf(aij, w.w, acc[i].w);
        }
      }
    }
#pragma unroll
    for (int i = 0; i < 8; ++i) {
      long long r = rbase + i;
      if (r < N) C4[r * 32 + cg] = acc[i];
    }
  }
}

// agg[i,:] = b + h[i,:] * dinv[i]^2   (bias + self-loop message)
__global__ __launch_bounds__(TPB) void k_init_agg(float4* __restrict__ agg,
                                                  const float4* __restrict__ h,
                                                  const float* __restrict__ dinv,
                                                  const float4* __restrict__ b,
                                                  long long n32) {
  long long t = (long long)blockIdx.x * TPB + threadIdx.x;
  if (t >= n32) return;
  int i = (int)(t >> 5), c = (int)(t & 31);
  float di = dinv[i];
  float s = di * di;
  float4 hv = h[t];
  float4 bv = b[c];
  float4 o;
  o.x = fmaf(hv.x, s, bv.x);
  o.y = fmaf(hv.y, s, bv.y);
  o.z = fmaf(hv.z, s, bv.z);
  o.w = fmaf(hv.w, s, bv.w);
  agg[t] = o;
}

// agg[dst,:] += h[src,:] * norm[e]; 32 lanes per edge, float4 each.
__global__ __launch_bounds__(TPB) void k_scatter(float* __restrict__ agg,
                                                 const float4* __restrict__ h,
                                                 const float* __restrict__ norm,
                                                 const int* __restrict__ ei,
                                                 long long E) {
  long long t = (long long)blockIdx.x * TPB + threadIdx.x;
  long long e = t >> 5;
  if (e >= E) return;
  int c = (int)(t & 31);
  int s = ei[e];
  int d = ei[E + e];
  float nm = norm[e];
  float4 hv = h[(long long)s * 32 + c];
  float* out = agg + (long long)d * 128 + (c << 2);
  gatomic_add(out + 0, hv.x * nm);
  gatomic_add(out + 1, hv.y * nm);
  gatomic_add(out + 2, hv.z * nm);
  gatomic_add(out + 3, hv.w * nm);
}

__global__ __launch_bounds__(TPB) void k_relu(float4* __restrict__ x, long long n4) {
  long long t = (long long)blockIdx.x * TPB + threadIdx.x;
  if (t >= n4) return;
  float4 v = x[t];
  v.x = fmaxf(v.x, 0.f);
  v.y = fmaxf(v.y, 0.f);
  v.z = fmaxf(v.z, 0.f);
  v.w = fmaxf(v.w, 0.f);
  x[t] = v;
}

extern "C" void kernel_launch(void* const* d_in, const int* in_sizes, int n_in,
                              void* d_out, int out_size, void* d_ws, size_t ws_size,
                              hipStream_t stream) {
  const float* x  = (const float*)d_in[0];
  const float* W1 = (const float*)d_in[1];
  const float* b1 = (const float*)d_in[2];
  const float* W2 = (const float*)d_in[3];
  const float* b2 = (const float*)d_in[4];
  const int*   ei = (const int*)d_in[5];   // [2,E] int32 (src row, dst row)

  const int N = in_sizes[0] / 128;
  const long long E = in_sizes[5] / 2;

  float* ws   = (float*)d_ws;
  float* dinv = ws;                               // N floats (deg, then rsqrt in place)
  float* norm = dinv + N;                          // E floats
  float* h    = norm + E;                          // N*128 floats
  float* agg1 = h + (long long)N * 128;            // N*128 floats
  float* out  = (float*)d_out;

  const int gN = (N + TPB - 1) / TPB;
  const int gE = (int)((E + TPB - 1) / TPB);
  const long long n32 = (long long)N * 32;
  const int gN32 = (int)((n32 + TPB - 1) / TPB);
  const long long e32 = E * 32;
  const int gE32 = (int)((e32 + TPB - 1) / TPB);
  const int gGemm = (N + 63) / 64;

  // degree -> dinv -> per-edge norm
  k_init_deg<<<gN, TPB, 0, stream>>>(dinv, N);
  k_count_deg<<<gE, TPB, 0, stream>>>(dinv, ei, E);
  k_dinv<<<gN, TPB, 0, stream>>>(dinv, N);
  k_edge_norm<<<gE, TPB, 0, stream>>>(norm, dinv, ei, E);

  // layer 1
  k_gemm128<0><<<gGemm, TPB, 0, stream>>>(x, W1, h, N);
  k_init_agg<<<gN32, TPB, 0, stream>>>((float4*)agg1, (const float4*)h, dinv,
                                       (const float4*)b1, n32);
  k_scatter<<<gE32, TPB, 0, stream>>>(agg1, (const float4*)h, norm, ei, E);

  // layer 2 (relu fused into GEMM A-load; scatter straight into d_out)
  k_gemm128<1><<<gGemm, TPB, 0, stream>>>(agg1, W2, h, N);
  k_init_agg<<<gN32, TPB, 0, stream>>>((float4*)out, (const float4*)h, dinv,
                                       (const float4*)b2, n32);
  k_scatter<<<gE32, TPB, 0, stream>>>(out, (const float4*)h, norm, ei, E);

  k_relu<<<gN32, TPB, 0, stream>>>((float4*)out, n32);
}

// Round 2
// 802.620 us; speedup vs baseline: 7.2227x; 7.2227x over previous
//
#include <hip/hip_runtime.h>

#define TPB 256

// ---------------- edge preprocessing: counting sort by dst ----------------

__global__ __launch_bounds__(TPB) void k_zero_i32(int* __restrict__ p, int n) {
  int i = blockIdx.x * TPB + threadIdx.x;
  if (i < n) p[i] = 0;
}

__global__ __launch_bounds__(TPB) void k_hist(int* __restrict__ cnt,
                                              const int* __restrict__ ei,
                                              long long E) {
  long long e = (long long)blockIdx.x * TPB + threadIdx.x;
  if (e < E) atomicAdd(&cnt[ei[E + e]], 1);
}

// per-256-chunk exclusive scan of cnt -> off, chunk totals -> part
__global__ __launch_bounds__(TPB) void k_blockscan(const int* __restrict__ cnt,
                                                   int* __restrict__ off,
                                                   int* __restrict__ part, int n) {
  __shared__ int lds[TPB];
  int gid = blockIdx.x * TPB + threadIdx.x;
  int v = (gid < n) ? cnt[gid] : 0;
  lds[threadIdx.x] = v;
  __syncthreads();
#pragma unroll
  for (int ofs = 1; ofs < TPB; ofs <<= 1) {
    int t = (threadIdx.x >= ofs) ? lds[threadIdx.x - ofs] : 0;
    __syncthreads();
    lds[threadIdx.x] += t;
    __syncthreads();
  }
  int incl = lds[threadIdx.x];
  if (gid < n) off[gid] = incl - v;
  if (threadIdx.x == TPB - 1) part[blockIdx.x] = incl;
}

// single-block exclusive scan of part[B], B <= 512
__global__ __launch_bounds__(512) void k_scanpart(int* __restrict__ part, int B) {
  __shared__ int lds[512];
  int v = (threadIdx.x < B) ? part[threadIdx.x] : 0;
  lds[threadIdx.x] = v;
  __syncthreads();
#pragma unroll
  for (int ofs = 1; ofs < 512; ofs <<= 1) {
    int t = (threadIdx.x >= ofs) ? lds[threadIdx.x - ofs] : 0;
    __syncthreads();
    lds[threadIdx.x] += t;
    __syncthreads();
  }
  if (threadIdx.x < B) part[threadIdx.x] = lds[threadIdx.x] - v;
}

// off += scanned part; pos = off; dinv = rsqrt(1 + cnt)
__global__ __launch_bounds__(TPB) void k_finalize_off(int* __restrict__ off,
                                                      int* __restrict__ pos,
                                                      float* __restrict__ dinv,
                                                      const int* __restrict__ part,
                                                      const int* __restrict__ cnt,
                                                      int n) {
  int gid = blockIdx.x * TPB + threadIdx.x;
  if (gid >= n) return;
  int o = off[gid] + part[blockIdx.x];
  off[gid] = o;
  pos[gid] = o;
  dinv[gid] = rsqrtf(1.0f + (float)cnt[gid]);
}

// scatter each edge's payload (src, dinv[src]) to its sorted-by-dst slot
__global__ __launch_bounds__(TPB) void k_scatter_sort(int2* __restrict__ pay,
                                                      int* __restrict__ pos,
                                                      const float* __restrict__ dinv,
                                                      const int* __restrict__ ei,
                                                      long long E) {
  long long e = (long long)blockIdx.x * TPB + threadIdx.x;
  if (e >= E) return;
  int s = ei[e];
  int d = ei[E + e];
  int p = atomicAdd(&pos[d], 1);
  pay[p] = make_int2(s, __float_as_int(dinv[s]));
}

// ---------------- dense GEMM: C[N,128] = (relu?)(A)[N,128] @ W[128,128] -----

template <int RELU>
__global__ __launch_bounds__(TPB) void k_gemm128(const float* __restrict__ A,
                                                 const float* __restrict__ W,
                                                 float* __restrict__ C, int N) {
  __shared__ float Wlds[128 * 128];
  {
    const float4* W4 = (const float4*)W;
    float4* Wl4w = (float4*)Wlds;
    for (int i = threadIdx.x; i < 128 * 32; i += TPB) Wl4w[i] = W4[i];
  }
  __syncthreads();
  const float4* Wl4 = (const float4*)Wlds;
  const int rt = threadIdx.x >> 5;   // 0..7
  const int cg = threadIdx.x & 31;   // 0..31
  const float4* A4 = (const float4*)A;
  float4* C4 = (float4*)C;

  for (long long row0 = (long long)blockIdx.x * 64; row0 < N;
       row0 += (long long)gridDim.x * 64) {
    const long long rbase = row0 + (long long)rt * 8;
    float4 acc[8];
#pragma unroll
    for (int i = 0; i < 8; ++i) acc[i] = make_float4(0.f, 0.f, 0.f, 0.f);

    for (int kk = 0; kk < 32; ++kk) {
      float4 av[8];
#pragma unroll
      for (int i = 0; i < 8; ++i) {
        long long r = rbase + i;
        av[i] = (r < N) ? A4[r * 32 + kk] : make_float4(0.f, 0.f, 0.f, 0.f);
        if (RELU) {
          av[i].x = fmaxf(av[i].x, 0.f);
          av[i].y = fmaxf(av[i].y, 0.f);
          av[i].z = fmaxf(av[i].z, 0.f);
          av[i].w = fmaxf(av[i].w, 0.f);
        }
      }
#pragma unroll
      for (int j = 0; j < 4; ++j) {
        float4 w = Wl4[(kk * 4 + j) * 32 + cg];
#pragma unroll
        for (int i = 0; i < 8; ++i) {
          float aij = ((const float*)&av[i])[j];
          acc[i].x = fmaf(aij, w.x, acc[i].x);
          acc[i].y = fmaf(aij, w.y, acc[i].y);
          acc[i].z = fmaf(aij, w.z, acc[i].z);
          acc[i].w = fmaf(aij, w.w, acc[i].w);
        }
      }
    }
#pragma unroll
    for (int i = 0; i < 8; ++i) {
      long long r = rbase + i;
      if (r < N) C4[r * 32 + cg] = acc[i];
    }
  }
}

// ---------------- gather-reduce aggregation (no atomics) --------------------
// out[i,:] = b + dinv[i] * ( dinv[i]*h[i,:] + sum_{e: dst=i} dinv[src]*h[src,:] )
// one 32-lane group per node, float4 per lane.
__global__ __launch_bounds__(TPB) void k_agg(float4* __restrict__ out,
                                             const float4* __restrict__ h,
                                             const int2* __restrict__ pay,
                                             const int* __restrict__ off,
                                             const int* __restrict__ cnt,
                                             const float* __restrict__ dinv,
                                             const float4* __restrict__ b, int N) {
  long long t = (long long)blockIdx.x * TPB + threadIdx.x;
  int g = (int)(t >> 5);
  if (g >= N) return;
  int c = (int)(t & 31);
  float di = dinv[g];

  float4 hv = h[(long long)g * 32 + c];
  float4 acc;
  acc.x = hv.x * di;
  acc.y = hv.y * di;
  acc.z = hv.z * di;
  acc.w = hv.w * di;

  int p = off[g];
  int en = p + cnt[g];
  for (; p < en; ++p) {
    int2 pl = pay[p];
    float dv = __int_as_float(pl.y);
    float4 sv = h[(long long)pl.x * 32 + c];
    acc.x = fmaf(sv.x, dv, acc.x);
    acc.y = fmaf(sv.y, dv, acc.y);
    acc.z = fmaf(sv.z, dv, acc.z);
    acc.w = fmaf(sv.w, dv, acc.w);
  }

  float4 bv = b[c];
  float4 o;
  o.x = fmaf(acc.x, di, bv.x);
  o.y = fmaf(acc.y, di, bv.y);
  o.z = fmaf(acc.z, di, bv.z);
  o.w = fmaf(acc.w, di, bv.w);
  out[(long long)g * 32 + c] = o;
}

__global__ __launch_bounds__(TPB) void k_relu(float4* __restrict__ x, long long n4) {
  long long t = (long long)blockIdx.x * TPB + threadIdx.x;
  if (t >= n4) return;
  float4 v = x[t];
  v.x = fmaxf(v.x, 0.f);
  v.y = fmaxf(v.y, 0.f);
  v.z = fmaxf(v.z, 0.f);
  v.w = fmaxf(v.w, 0.f);
  x[t] = v;
}

// ---------------------------------------------------------------------------

extern "C" void kernel_launch(void* const* d_in, const int* in_sizes, int n_in,
                              void* d_out, int out_size, void* d_ws, size_t ws_size,
                              hipStream_t stream) {
  const float* x  = (const float*)d_in[0];
  const float* W1 = (const float*)d_in[1];
  const float* b1 = (const float*)d_in[2];
  const float* W2 = (const float*)d_in[3];
  const float* b2 = (const float*)d_in[4];
  const int*   ei = (const int*)d_in[5];   // [2,E] int32

  const int N = in_sizes[0] / 128;
  const long long E = in_sizes[5] / 2;

  // ws layout
  char* w = (char*)d_ws;
  int*   cnt  = (int*)w;                 w += (size_t)N * 4;
  int*   off  = (int*)w;                 w += (size_t)N * 4;
  int*   pos  = (int*)w;                 w += (size_t)N * 4;
  int*   part = (int*)w;                 w += 512 * 4;
  float* dinv = (float*)w;               w += (size_t)N * 4;
  int2*  pay  = (int2*)w;                w += (size_t)E * 8;
  float* h    = (float*)w;               // N*128 floats

  float* out = (float*)d_out;

  const int gN  = (N + TPB - 1) / TPB;           // 391
  const int gE  = (int)((E + TPB - 1) / TPB);
  const long long n32 = (long long)N * 32;
  const int gN32 = (int)((n32 + TPB - 1) / TPB);
  const int gGemm = (N + 63) / 64;

  // ---- counting sort of edges by dst + dinv ----
  k_zero_i32<<<gN, TPB, 0, stream>>>(cnt, N);
  k_hist<<<gE, TPB, 0, stream>>>(cnt, ei, E);
  k_blockscan<<<gN, TPB, 0, stream>>>(cnt, off, part, N);
  k_scanpart<<<1, 512, 0, stream>>>(part, gN);
  k_finalize_off<<<gN, TPB, 0, stream>>>(off, pos, dinv, part, cnt, N);
  k_scatter_sort<<<gE, TPB, 0, stream>>>(pay, pos, dinv, ei, E);

  // ---- layer 1: h = x@W1 ; d_out = b1 + norm-agg(h) ----
  k_gemm128<0><<<gGemm, TPB, 0, stream>>>(x, W1, h, N);
  k_agg<<<gN32, TPB, 0, stream>>>((float4*)out, (const float4*)h, pay, off, cnt,
                                  dinv, (const float4*)b1, N);

  // ---- layer 2: h = relu(d_out)@W2 ; d_out = b2 + norm-agg(h) ; relu ----
  k_gemm128<1><<<gGemm, TPB, 0, stream>>>(out, W2, h, N);
  k_agg<<<gN32, TPB, 0, stream>>>((float4*)out, (const float4*)h, pay, off, cnt,
                                  dinv, (const float4*)b2, N);
  k_relu<<<gN32, TPB, 0, stream>>>((float4*)out, n32);
}

// Round 3
// 576.664 us; speedup vs baseline: 10.0527x; 1.3918x over previous
//
#include <hip/hip_runtime.h>

#define TPB 256

// ---------------- edge preprocessing: counting sort by dst ----------------

__global__ __launch_bounds__(TPB) void k_zero_i32(int* __restrict__ p, int n) {
  int i = blockIdx.x * TPB + threadIdx.x;
  if (i < n) p[i] = 0;
}

__global__ __launch_bounds__(TPB) void k_hist(int* __restrict__ cnt,
                                              const int* __restrict__ ei,
                                              long long E) {
  long long e = (long long)blockIdx.x * TPB + threadIdx.x;
  if (e < E) atomicAdd(&cnt[ei[E + e]], 1);
}

// per-256-chunk exclusive scan of cnt -> off, chunk totals -> part
__global__ __launch_bounds__(TPB) void k_blockscan(const int* __restrict__ cnt,
                                                   int* __restrict__ off,
                                                   int* __restrict__ part, int n) {
  __shared__ int lds[TPB];
  int gid = blockIdx.x * TPB + threadIdx.x;
  int v = (gid < n) ? cnt[gid] : 0;
  lds[threadIdx.x] = v;
  __syncthreads();
#pragma unroll
  for (int ofs = 1; ofs < TPB; ofs <<= 1) {
    int t = (threadIdx.x >= ofs) ? lds[threadIdx.x - ofs] : 0;
    __syncthreads();
    lds[threadIdx.x] += t;
    __syncthreads();
  }
  int incl = lds[threadIdx.x];
  if (gid < n) off[gid] = incl - v;
  if (threadIdx.x == TPB - 1) part[blockIdx.x] = incl;
}

// single-block exclusive scan of part[B], B <= 512
__global__ __launch_bounds__(512) void k_scanpart(int* __restrict__ part, int B) {
  __shared__ int lds[512];
  int v = (threadIdx.x < B) ? part[threadIdx.x] : 0;
  lds[threadIdx.x] = v;
  __syncthreads();
#pragma unroll
  for (int ofs = 1; ofs < 512; ofs <<= 1) {
    int t = (threadIdx.x >= ofs) ? lds[threadIdx.x - ofs] : 0;
    __syncthreads();
    lds[threadIdx.x] += t;
    __syncthreads();
  }
  if (threadIdx.x < B) part[threadIdx.x] = lds[threadIdx.x] - v;
}

// off += scanned part; pos = off; dinv = rsqrt(1 + cnt)
__global__ __launch_bounds__(TPB) void k_finalize_off(int* __restrict__ off,
                                                      int* __restrict__ pos,
                                                      float* __restrict__ dinv,
                                                      const int* __restrict__ part,
                                                      const int* __restrict__ cnt,
                                                      int n) {
  int gid = blockIdx.x * TPB + threadIdx.x;
  if (gid >= n) return;
  int o = off[gid] + part[blockIdx.x];
  off[gid] = o;
  pos[gid] = o;
  dinv[gid] = rsqrtf(1.0f + (float)cnt[gid]);
}

// scatter each edge's payload (src, dinv[src]) to its sorted-by-dst slot
__global__ __launch_bounds__(TPB) void k_scatter_sort(int2* __restrict__ pay,
                                                      int* __restrict__ pos,
                                                      const float* __restrict__ dinv,
                                                      const int* __restrict__ ei,
                                                      long long E) {
  long long e = (long long)blockIdx.x * TPB + threadIdx.x;
  if (e >= E) return;
  int s = ei[e];
  int d = ei[E + e];
  int p = atomicAdd(&pos[d], 1);
  pay[p] = make_int2(s, __float_as_int(dinv[s]));
}

// ------------- dense GEMM: C[N,128] = (relu?)(A)[N,128] @ W[128,128] --------
// 128x128 block tile, 256 threads, 8x8 per thread. A tile (stride 129, bank-
// conflict-free) + full W staged in LDS (130.5 KB total, 1 block/CU).
#define ASTRIDE 129

template <int RELU>
__global__ __launch_bounds__(TPB) void k_gemm128(const float* __restrict__ A,
                                                 const float* __restrict__ W,
                                                 float* __restrict__ C, int N) {
  __shared__ float Ws[128 * 128];
  __shared__ float As[128 * ASTRIDE];
  const int tid = threadIdx.x;
  const long long row0 = (long long)blockIdx.x * 128;

  // stage W (row-major [k][n], read via 4-addr broadcast -> conflict-free)
  {
    const float4* W4 = (const float4*)W;
    float4* Ws4 = (float4*)Ws;
#pragma unroll
    for (int i = 0; i < 16; ++i) Ws4[i * TPB + tid] = W4[i * TPB + tid];
  }
  // stage A tile: 128 rows x 128 k, coalesced global float4, b32 LDS writes
  {
    const float4* A4 = (const float4*)A;
#pragma unroll
    for (int i = 0; i < 16; ++i) {
      int l = i * TPB + tid;
      int r = l >> 5;        // 0..127
      int kq = l & 31;       // 0..31
      long long gr = row0 + r;
      float4 v = (gr < (long long)N) ? A4[gr * 32 + kq]
                                     : make_float4(0.f, 0.f, 0.f, 0.f);
      if (RELU) {
        v.x = fmaxf(v.x, 0.f); v.y = fmaxf(v.y, 0.f);
        v.z = fmaxf(v.z, 0.f); v.w = fmaxf(v.w, 0.f);
      }
      float* dst = &As[r * ASTRIDE + (kq << 2)];
      dst[0] = v.x; dst[1] = v.y; dst[2] = v.z; dst[3] = v.w;
    }
  }
  __syncthreads();

  const int tx = tid & 15;   // row group: rows tx + 16j
  const int ty = tid >> 4;   // col group: cols ty*4 and ty*4+64
  float4 acc[8][2];
#pragma unroll
  for (int j = 0; j < 8; ++j) {
    acc[j][0] = make_float4(0.f, 0.f, 0.f, 0.f);
    acc[j][1] = make_float4(0.f, 0.f, 0.f, 0.f);
  }

#pragma unroll 4
  for (int k = 0; k < 128; ++k) {
    const float4 wlo = *(const float4*)&Ws[k * 128 + (ty << 2)];
    const float4 whi = *(const float4*)&Ws[k * 128 + (ty << 2) + 64];
    float a[8];
#pragma unroll
    for (int j = 0; j < 8; ++j) a[j] = As[(tx + (j << 4)) * ASTRIDE + k];
#pragma unroll
    for (int j = 0; j < 8; ++j) {
      acc[j][0].x = fmaf(a[j], wlo.x, acc[j][0].x);
      acc[j][0].y = fmaf(a[j], wlo.y, acc[j][0].y);
      acc[j][0].z = fmaf(a[j], wlo.z, acc[j][0].z);
      acc[j][0].w = fmaf(a[j], wlo.w, acc[j][0].w);
      acc[j][1].x = fmaf(a[j], whi.x, acc[j][1].x);
      acc[j][1].y = fmaf(a[j], whi.y, acc[j][1].y);
      acc[j][1].z = fmaf(a[j], whi.z, acc[j][1].z);
      acc[j][1].w = fmaf(a[j], whi.w, acc[j][1].w);
    }
  }

  float4* C4 = (float4*)C;
#pragma unroll
  for (int j = 0; j < 8; ++j) {
    long long r = row0 + tx + (j << 4);
    if (r < (long long)N) {
      C4[r * 32 + ty] = acc[j][0];
      C4[r * 32 + ty + 16] = acc[j][1];
    }
  }
}

// ---------------- gather-reduce aggregation (no atomics) --------------------
// out[i,:] = b + dinv[i] * ( dinv[i]*h[i,:] + sum_{e: dst=i} dinv[src]*h[src,:] )
// one 32-lane group per node, float4 per lane; 4-deep unrolled gather for ILP.
template <int RELU>
__global__ __launch_bounds__(TPB) void k_agg(float4* __restrict__ out,
                                             const float4* __restrict__ h,
                                             const int2* __restrict__ pay,
                                             const int* __restrict__ off,
                                             const int* __restrict__ cnt,
                                             const float* __restrict__ dinv,
                                             const float4* __restrict__ b, int N) {
  long long t = (long long)blockIdx.x * TPB + threadIdx.x;
  int g = (int)(t >> 5);
  if (g >= N) return;
  int c = (int)(t & 31);
  float di = dinv[g];

  float4 hv = h[(long long)g * 32 + c];
  float4 acc;
  acc.x = hv.x * di;
  acc.y = hv.y * di;
  acc.z = hv.z * di;
  acc.w = hv.w * di;

  int p = off[g];
  const int en = p + cnt[g];

  for (; p + 4 <= en; p += 4) {
    int2 a0 = pay[p], a1 = pay[p + 1], a2 = pay[p + 2], a3 = pay[p + 3];
    float4 s0 = h[(long long)a0.x * 32 + c];
    float4 s1 = h[(long long)a1.x * 32 + c];
    float4 s2 = h[(long long)a2.x * 32 + c];
    float4 s3 = h[(long long)a3.x * 32 + c];
    float d0 = __int_as_float(a0.y), d1 = __int_as_float(a1.y);
    float d2 = __int_as_float(a2.y), d3 = __int_as_float(a3.y);
    acc.x = fmaf(s0.x, d0, acc.x); acc.y = fmaf(s0.y, d0, acc.y);
    acc.z = fmaf(s0.z, d0, acc.z); acc.w = fmaf(s0.w, d0, acc.w);
    acc.x = fmaf(s1.x, d1, acc.x); acc.y = fmaf(s1.y, d1, acc.y);
    acc.z = fmaf(s1.z, d1, acc.z); acc.w = fmaf(s1.w, d1, acc.w);
    acc.x = fmaf(s2.x, d2, acc.x); acc.y = fmaf(s2.y, d2, acc.y);
    acc.z = fmaf(s2.z, d2, acc.z); acc.w = fmaf(s2.w, d2, acc.w);
    acc.x = fmaf(s3.x, d3, acc.x); acc.y = fmaf(s3.y, d3, acc.y);
    acc.z = fmaf(s3.z, d3, acc.z); acc.w = fmaf(s3.w, d3, acc.w);
  }
  for (; p < en; ++p) {
    int2 pl = pay[p];
    float dv = __int_as_float(pl.y);
    float4 sv = h[(long long)pl.x * 32 + c];
    acc.x = fmaf(sv.x, dv, acc.x); acc.y = fmaf(sv.y, dv, acc.y);
    acc.z = fmaf(sv.z, dv, acc.z); acc.w = fmaf(sv.w, dv, acc.w);
  }

  float4 bv = b[c];
  float4 o;
  o.x = fmaf(acc.x, di, bv.x);
  o.y = fmaf(acc.y, di, bv.y);
  o.z = fmaf(acc.z, di, bv.z);
  o.w = fmaf(acc.w, di, bv.w);
  if (RELU) {
    o.x = fmaxf(o.x, 0.f); o.y = fmaxf(o.y, 0.f);
    o.z = fmaxf(o.z, 0.f); o.w = fmaxf(o.w, 0.f);
  }
  out[(long long)g * 32 + c] = o;
}

// ---------------------------------------------------------------------------

extern "C" void kernel_launch(void* const* d_in, const int* in_sizes, int n_in,
                              void* d_out, int out_size, void* d_ws, size_t ws_size,
                              hipStream_t stream) {
  const float* x  = (const float*)d_in[0];
  const float* W1 = (const float*)d_in[1];
  const float* b1 = (const float*)d_in[2];
  const float* W2 = (const float*)d_in[3];
  const float* b2 = (const float*)d_in[4];
  const int*   ei = (const int*)d_in[5];   // [2,E] int32

  const int N = in_sizes[0] / 128;
  const long long E = in_sizes[5] / 2;

  // ws layout
  char* w = (char*)d_ws;
  int*   cnt  = (int*)w;                 w += (size_t)N * 4;
  int*   off  = (int*)w;                 w += (size_t)N * 4;
  int*   pos  = (int*)w;                 w += (size_t)N * 4;
  int*   part = (int*)w;                 w += 512 * 4;
  float* dinv = (float*)w;               w += (size_t)N * 4;
  int2*  pay  = (int2*)w;                w += (size_t)E * 8;
  float* h    = (float*)w;               // N*128 floats

  float* out = (float*)d_out;

  const int gN  = (N + TPB - 1) / TPB;           // 391
  const int gE  = (int)((E + TPB - 1) / TPB);
  const long long n32 = (long long)N * 32;
  const int gN32 = (int)((n32 + TPB - 1) / TPB);
  const int gGemm = (N + 127) / 128;

  // ---- counting sort of edges by dst + dinv ----
  k_zero_i32<<<gN, TPB, 0, stream>>>(cnt, N);
  k_hist<<<gE, TPB, 0, stream>>>(cnt, ei, E);
  k_blockscan<<<gN, TPB, 0, stream>>>(cnt, off, part, N);
  k_scanpart<<<1, 512, 0, stream>>>(part, gN);
  k_finalize_off<<<gN, TPB, 0, stream>>>(off, pos, dinv, part, cnt, N);
  k_scatter_sort<<<gE, TPB, 0, stream>>>(pay, pos, dinv, ei, E);

  // ---- layer 1: h = x@W1 ; d_out = b1 + norm-agg(h) ----
  k_gemm128<0><<<gGemm, TPB, 0, stream>>>(x, W1, h, N);
  k_agg<0><<<gN32, TPB, 0, stream>>>((float4*)out, (const float4*)h, pay, off,
                                     cnt, dinv, (const float4*)b1, N);

  // ---- layer 2: h = relu(d_out)@W2 ; d_out = relu(b2 + norm-agg(h)) ----
  k_gemm128<1><<<gGemm, TPB, 0, stream>>>(out, W2, h, N);
  k_agg<1><<<gN32, TPB, 0, stream>>>((float4*)out, (const float4*)h, pay, off,
                                     cnt, dinv, (const float4*)b2, N);
}

// Round 4
// 535.773 us; speedup vs baseline: 10.8200x; 1.0763x over previous
//
#include <hip/hip_runtime.h>

#define TPB 256

// ---------------- edge preprocessing: counting sort by dst ----------------

__global__ __launch_bounds__(TPB) void k_zero_i32(int* __restrict__ p, int n) {
  int i = blockIdx.x * TPB + threadIdx.x;
  if (i < n) p[i] = 0;
}

__global__ __launch_bounds__(TPB) void k_hist(int* __restrict__ cnt,
                                              const int* __restrict__ ei,
                                              long long E) {
  long long e = (long long)blockIdx.x * TPB + threadIdx.x;
  if (e < E) atomicAdd(&cnt[ei[E + e]], 1);
}

// per-256-chunk exclusive scan of cnt -> off, chunk totals -> part
__global__ __launch_bounds__(TPB) void k_blockscan(const int* __restrict__ cnt,
                                                   int* __restrict__ off,
                                                   int* __restrict__ part, int n) {
  __shared__ int lds[TPB];
  int gid = blockIdx.x * TPB + threadIdx.x;
  int v = (gid < n) ? cnt[gid] : 0;
  lds[threadIdx.x] = v;
  __syncthreads();
#pragma unroll
  for (int ofs = 1; ofs < TPB; ofs <<= 1) {
    int t = (threadIdx.x >= ofs) ? lds[threadIdx.x - ofs] : 0;
    __syncthreads();
    lds[threadIdx.x] += t;
    __syncthreads();
  }
  int incl = lds[threadIdx.x];
  if (gid < n) off[gid] = incl - v;
  if (threadIdx.x == TPB - 1) part[blockIdx.x] = incl;
}

// single-block exclusive scan of part[B], B <= 512
__global__ __launch_bounds__(512) void k_scanpart(int* __restrict__ part, int B) {
  __shared__ int lds[512];
  int v = (threadIdx.x < B) ? part[threadIdx.x] : 0;
  lds[threadIdx.x] = v;
  __syncthreads();
#pragma unroll
  for (int ofs = 1; ofs < 512; ofs <<= 1) {
    int t = (threadIdx.x >= ofs) ? lds[threadIdx.x - ofs] : 0;
    __syncthreads();
    lds[threadIdx.x] += t;
    __syncthreads();
  }
  if (threadIdx.x < B) part[threadIdx.x] = lds[threadIdx.x] - v;
}

// off += scanned part; pos = off; dinv = rsqrt(1 + cnt)
__global__ __launch_bounds__(TPB) void k_finalize_off(int* __restrict__ off,
                                                      int* __restrict__ pos,
                                                      float* __restrict__ dinv,
                                                      const int* __restrict__ part,
                                                      const int* __restrict__ cnt,
                                                      int n) {
  int gid = blockIdx.x * TPB + threadIdx.x;
  if (gid >= n) return;
  int o = off[gid] + part[blockIdx.x];
  off[gid] = o;
  pos[gid] = o;
  dinv[gid] = rsqrtf(1.0f + (float)cnt[gid]);
}

// scatter each edge's payload (src, dinv[src]) to its sorted-by-dst slot
__global__ __launch_bounds__(TPB) void k_scatter_sort(int2* __restrict__ pay,
                                                      int* __restrict__ pos,
                                                      const float* __restrict__ dinv,
                                                      const int* __restrict__ ei,
                                                      long long E) {
  long long e = (long long)blockIdx.x * TPB + threadIdx.x;
  if (e >= E) return;
  int s = ei[e];
  int d = ei[E + e];
  int p = atomicAdd(&pos[d], 1);
  pay[p] = make_int2(s, __float_as_int(dinv[s]));
}

// ------------- dense GEMM: C[N,128] = (relu?)(A)[N,128] @ W[128,128] --------
// 128x128 tile, 512 threads (2 waves/SIMD), 8 rows x 4 cols per thread.
// As stored as float4 with row stride 33 float4s (132 floats): A b128 reads
// start at bank 4*tx -> 2 lanes/bank (free); W reads 4-addr broadcast (free).

template <int RELU>
__global__ __launch_bounds__(512) void k_gemm128(const float* __restrict__ A,
                                                 const float* __restrict__ W,
                                                 float* __restrict__ C, int N) {
  __shared__ float Ws[128 * 128];        // [k][n]
  __shared__ float As[128 * 132];        // [r][k], float4 stride 33
  const int tid = threadIdx.x;
  const long long row0 = (long long)blockIdx.x * 128;

  {
    const float4* W4 = (const float4*)W;
    float4* Ws4 = (float4*)Ws;
#pragma unroll
    for (int i = 0; i < 8; ++i) Ws4[i * 512 + tid] = W4[i * 512 + tid];
  }
  {
    const float4* A4 = (const float4*)A;
    float4* As4 = (float4*)As;
#pragma unroll
    for (int i = 0; i < 8; ++i) {
      int l = i * 512 + tid;
      int r = l >> 5;        // 0..127
      int kq = l & 31;       // float4 index along k
      long long gr = row0 + r;
      float4 v = (gr < (long long)N) ? A4[gr * 32 + kq]
                                     : make_float4(0.f, 0.f, 0.f, 0.f);
      if (RELU) {
        v.x = fmaxf(v.x, 0.f); v.y = fmaxf(v.y, 0.f);
        v.z = fmaxf(v.z, 0.f); v.w = fmaxf(v.w, 0.f);
      }
      As4[r * 33 + kq] = v;
    }
  }
  __syncthreads();

  const int tx = tid & 15;    // rows tx + 16j
  const int ty = tid >> 4;    // float4-col 0..31
  const float4* As4 = (const float4*)As;

  float4 acc[8];
#pragma unroll
  for (int j = 0; j < 8; ++j) acc[j] = make_float4(0.f, 0.f, 0.f, 0.f);

#pragma unroll 4
  for (int kk = 0; kk < 32; ++kk) {      // k in chunks of 4
    float4 a[8];
#pragma unroll
    for (int j = 0; j < 8; ++j) a[j] = As4[(tx + (j << 4)) * 33 + kk];
#pragma unroll
    for (int jj = 0; jj < 4; ++jj) {
      const float4 w = *(const float4*)&Ws[(kk * 4 + jj) * 128 + (ty << 2)];
#pragma unroll
      for (int j = 0; j < 8; ++j) {
        const float av = ((const float*)&a[j])[jj];
        acc[j].x = fmaf(av, w.x, acc[j].x);
        acc[j].y = fmaf(av, w.y, acc[j].y);
        acc[j].z = fmaf(av, w.z, acc[j].z);
        acc[j].w = fmaf(av, w.w, acc[j].w);
      }
    }
  }

  float4* C4 = (float4*)C;
#pragma unroll
  for (int j = 0; j < 8; ++j) {
    long long r = row0 + tx + (j << 4);
    if (r < (long long)N) C4[r * 32 + ty] = acc[j];
  }
}

// ---------------- gather-reduce aggregation (no atomics) --------------------
// out[i,:] = b + dinv[i] * ( dinv[i]*h[i,:] + sum_{e: dst=i} dinv[src]*h[src,:] )
// one 32-lane group per node, float4 per lane; 8-deep unrolled gather for MLP.
template <int RELU>
__global__ __launch_bounds__(TPB) void k_agg(float4* __restrict__ out,
                                             const float4* __restrict__ h,
                                             const int2* __restrict__ pay,
                                             const int* __restrict__ off,
                                             const int* __restrict__ cnt,
                                             const float* __restrict__ dinv,
                                             const float4* __restrict__ b, int N) {
  long long t = (long long)blockIdx.x * TPB + threadIdx.x;
  int g = (int)(t >> 5);
  if (g >= N) return;
  int c = (int)(t & 31);
  float di = dinv[g];
  float4 bv = b[c];

  float4 hv = h[(long long)g * 32 + c];
  float4 acc;
  acc.x = hv.x * di;
  acc.y = hv.y * di;
  acc.z = hv.z * di;
  acc.w = hv.w * di;

  int p = off[g];
  const int en = p + cnt[g];

  for (; p + 8 <= en; p += 8) {
    int2 a[8];
#pragma unroll
    for (int u = 0; u < 8; ++u) a[u] = pay[p + u];
    float4 s[8];
#pragma unroll
    for (int u = 0; u < 8; ++u) s[u] = h[(long long)a[u].x * 32 + c];
#pragma unroll
    for (int u = 0; u < 8; ++u) {
      float dv = __int_as_float(a[u].y);
      acc.x = fmaf(s[u].x, dv, acc.x);
      acc.y = fmaf(s[u].y, dv, acc.y);
      acc.z = fmaf(s[u].z, dv, acc.z);
      acc.w = fmaf(s[u].w, dv, acc.w);
    }
  }
  if (p + 4 <= en) {
    int2 a[4];
#pragma unroll
    for (int u = 0; u < 4; ++u) a[u] = pay[p + u];
    float4 s[4];
#pragma unroll
    for (int u = 0; u < 4; ++u) s[u] = h[(long long)a[u].x * 32 + c];
#pragma unroll
    for (int u = 0; u < 4; ++u) {
      float dv = __int_as_float(a[u].y);
      acc.x = fmaf(s[u].x, dv, acc.x);
      acc.y = fmaf(s[u].y, dv, acc.y);
      acc.z = fmaf(s[u].z, dv, acc.z);
      acc.w = fmaf(s[u].w, dv, acc.w);
    }
    p += 4;
  }
  for (; p < en; ++p) {
    int2 pl = pay[p];
    float dv = __int_as_float(pl.y);
    float4 sv = h[(long long)pl.x * 32 + c];
    acc.x = fmaf(sv.x, dv, acc.x); acc.y = fmaf(sv.y, dv, acc.y);
    acc.z = fmaf(sv.z, dv, acc.z); acc.w = fmaf(sv.w, dv, acc.w);
  }

  float4 o;
  o.x = fmaf(acc.x, di, bv.x);
  o.y = fmaf(acc.y, di, bv.y);
  o.z = fmaf(acc.z, di, bv.z);
  o.w = fmaf(acc.w, di, bv.w);
  if (RELU) {
    o.x = fmaxf(o.x, 0.f); o.y = fmaxf(o.y, 0.f);
    o.z = fmaxf(o.z, 0.f); o.w = fmaxf(o.w, 0.f);
  }
  out[(long long)g * 32 + c] = o;
}

// ---------------------------------------------------------------------------

extern "C" void kernel_launch(void* const* d_in, const int* in_sizes, int n_in,
                              void* d_out, int out_size, void* d_ws, size_t ws_size,
                              hipStream_t stream) {
  const float* x  = (const float*)d_in[0];
  const float* W1 = (const float*)d_in[1];
  const float* b1 = (const float*)d_in[2];
  const float* W2 = (const float*)d_in[3];
  const float* b2 = (const float*)d_in[4];
  const int*   ei = (const int*)d_in[5];   // [2,E] int32

  const int N = in_sizes[0] / 128;
  const long long E = in_sizes[5] / 2;

  // ws layout
  char* w = (char*)d_ws;
  int*   cnt  = (int*)w;                 w += (size_t)N * 4;
  int*   off  = (int*)w;                 w += (size_t)N * 4;
  int*   pos  = (int*)w;                 w += (size_t)N * 4;
  int*   part = (int*)w;                 w += 512 * 4;
  float* dinv = (float*)w;               w += (size_t)N * 4;
  int2*  pay  = (int2*)w;                w += (size_t)E * 8;
  float* h    = (float*)w;               // N*128 floats

  float* out = (float*)d_out;

  const int gN  = (N + TPB - 1) / TPB;           // 391
  const int gE  = (int)((E + TPB - 1) / TPB);
  const long long n32 = (long long)N * 32;
  const int gN32 = (int)((n32 + TPB - 1) / TPB);
  const int gGemm = (N + 127) / 128;

  // ---- counting sort of edges by dst + dinv ----
  k_zero_i32<<<gN, TPB, 0, stream>>>(cnt, N);
  k_hist<<<gE, TPB, 0, stream>>>(cnt, ei, E);
  k_blockscan<<<gN, TPB, 0, stream>>>(cnt, off, part, N);
  k_scanpart<<<1, 512, 0, stream>>>(part, gN);
  k_finalize_off<<<gN, TPB, 0, stream>>>(off, pos, dinv, part, cnt, N);
  k_scatter_sort<<<gE, TPB, 0, stream>>>(pay, pos, dinv, ei, E);

  // ---- layer 1: h = x@W1 ; d_out = b1 + norm-agg(h) ----
  k_gemm128<0><<<gGemm, 512, 0, stream>>>(x, W1, h, N);
  k_agg<0><<<gN32, TPB, 0, stream>>>((float4*)out, (const float4*)h, pay, off,
                                     cnt, dinv, (const float4*)b1, N);

  // ---- layer 2: h = relu(d_out)@W2 ; d_out = relu(b2 + norm-agg(h)) ----
  k_gemm128<1><<<gGemm, 512, 0, stream>>>(out, W2, h, N);
  k_agg<1><<<gN32, TPB, 0, stream>>>((float4*)out, (const float4*)h, pay, off,
                                     cnt, dinv, (const float4*)b2, N);
}